// Round 9
// baseline (332.515 us; speedup 1.0000x reference)
//
#include <hip/hip_runtime.h>
#include <hip/hip_bf16.h>
#include <stdint.h>

typedef unsigned short u16;
typedef unsigned int   u32;

using short8 = __attribute__((ext_vector_type(8))) short;
using f32x4  = __attribute__((ext_vector_type(4))) float;

// ---------- bf16 helpers (raw-bit, RNE store) ----------
__device__ __forceinline__ float b2f(u32 u) {
    union { u32 i; float f; } v;
    v.i = u << 16;
    return v.f;
}
__device__ __forceinline__ u16 f2b(float f) {
    union { float f; u32 i; } v; v.f = f;
    u32 x = v.i;
    x += 0x7fffu + ((x >> 16) & 1u);   // round-to-nearest-even
    return (u16)(x >> 16);
}

// ---------- async global->LDS, 16B per lane ----------
__device__ __forceinline__ void gll16(const u16* g, u16* l) {
    __builtin_amdgcn_global_load_lds(
        (const __attribute__((address_space(1))) void*)g,
        (__attribute__((address_space(3))) void*)l, 16, 0, 0);
}

// ---------- prep: fp32 -> bf16 elementwise (8 elems/thread) ----------
__global__ __launch_bounds__(256)
void cast_bf16(const float* __restrict__ in, u16* __restrict__ out, int n)
{
    const int i = (blockIdx.x * 256 + threadIdx.x) * 8;
    if (i >= n) return;
    const float4 a = *reinterpret_cast<const float4*>(in + i);
    const float4 b = *reinterpret_cast<const float4*>(in + i + 4);
    u32 p0 = (u32)f2b(a.x) | ((u32)f2b(a.y) << 16);
    u32 p1 = (u32)f2b(a.z) | ((u32)f2b(a.w) << 16);
    u32 p2 = (u32)f2b(b.x) | ((u32)f2b(b.y) << 16);
    u32 p3 = (u32)f2b(b.z) | ((u32)f2b(b.w) << 16);
    *reinterpret_cast<uint4*>(out + i) = make_uint4(p0, p1, p2, p3);
}

// ---------- prep: W[R,Ncols] fp32 -> Wt[Ncols,R] bf16 (32x32 LDS tiles) ----------
__global__ __launch_bounds__(256)
void transpose_cast(const float* __restrict__ W, u16* __restrict__ Wt, int R, int Ncols)
{
    __shared__ float t[32][33];
    const int c0 = blockIdx.x * 32, r0 = blockIdx.y * 32;
    const int lx = threadIdx.x & 31, ly = threadIdx.x >> 5;   // 32 x 8
#pragma unroll
    for (int i = 0; i < 4; i++) {
        const int r = ly + i * 8;
        t[r][lx] = W[(size_t)(r0 + r) * Ncols + c0 + lx];
    }
    __syncthreads();
#pragma unroll
    for (int i = 0; i < 4; i++) {
        const int c = ly + i * 8;
        Wt[(size_t)(c0 + c) * R + r0 + lx] = f2b(t[lx][c]);
    }
}

// ---------- MFMA GEMM: C[M,N] = A[M,K] @ Bt[N,K]^T + bias[N] ----------
template<typename OT>
__global__ __launch_bounds__(256)
void gemm_mfma(const u16* __restrict__ A, const u16* __restrict__ Bt,
               const float* __restrict__ bias, OT* __restrict__ C,
               int M, int N, int K)
{
    __shared__ u16 As[128 * 32];   // [row][k], row stride 32
    __shared__ u16 Bs[128 * 32];   // [col][k]

    const int tid  = threadIdx.x;
    const int w    = tid >> 6;
    const int lane = tid & 63;
    const int quad = lane >> 4;
    const int c16  = lane & 15;
    const int wr   = w >> 1, wc = w & 1;

    const int m0 = blockIdx.y * 128;
    const int n0 = blockIdx.x * 128;

    const int srow = w * 32 + (lane >> 2);
    const int skc  = (lane & 3) * 8;
    const u16* gA = A  + (size_t)(m0 + srow) * K + skc;
    const u16* gB = Bt + (size_t)(n0 + srow) * K + skc;
    u16* lA = As + w * 32 * 32 + lane * 8;
    u16* lB = Bs + w * 32 * 32 + lane * 8;

    f32x4 acc[4][4];
#pragma unroll
    for (int i = 0; i < 4; i++)
#pragma unroll
        for (int j = 0; j < 4; j++) acc[i][j] = (f32x4){0.f, 0.f, 0.f, 0.f};

    for (int k0 = 0; k0 < K; k0 += 32) {
        __syncthreads();
        gll16(gA + k0,                  lA);
        gll16(gA + k0 + 16 * (size_t)K, lA + 16 * 32);
        gll16(gB + k0,                  lB);
        gll16(gB + k0 + 16 * (size_t)K, lB + 16 * 32);
        __syncthreads();

        short8 af[4], bf[4];
#pragma unroll
        for (int i = 0; i < 4; i++)
            af[i] = *reinterpret_cast<const short8*>(&As[(wr * 64 + i * 16 + c16) * 32 + quad * 8]);
#pragma unroll
        for (int j = 0; j < 4; j++)
            bf[j] = *reinterpret_cast<const short8*>(&Bs[(wc * 64 + j * 16 + c16) * 32 + quad * 8]);
#pragma unroll
        for (int i = 0; i < 4; i++)
#pragma unroll
            for (int j = 0; j < 4; j++)
                acc[i][j] = __builtin_amdgcn_mfma_f32_16x16x32_bf16(af[i], bf[j], acc[i][j], 0, 0, 0);
    }

#pragma unroll
    for (int i = 0; i < 4; i++)
#pragma unroll
        for (int j = 0; j < 4; j++) {
            const int colg = n0 + wc * 64 + j * 16 + c16;
            const float bv = bias[colg];
#pragma unroll
            for (int r = 0; r < 4; r++) {
                const int rowg = m0 + wr * 64 + i * 16 + quad * 4 + r;
                const float v = acc[i][j][r] + bv;
                if constexpr (sizeof(OT) == 2)
                    ((u16*)C)[(size_t)rowg * N + colg] = f2b(v);
                else
                    ((float*)C)[(size_t)rowg * N + colg] = v;
            }
        }
}

// ---------- Flash attention: paired q-tiles, S^T MFMA, LDS P-transform ----------
// Block x = 0..15 handles q-tiles {x, 31-x} (work sums to 33 tile-units for all
// blocks -> balanced 1024-block grid = 4 blocks/CU).
// S^T = K.Q^T (row=key, col=q); P via per-wave LDS roundtrip (no barrier).
constexpr int ALDP = 72;   // LDS row pad (u16 units)

struct TileState {
    f32x4 O[4];
    float m, l;
    short8 qf[2];
    int qglob;
};

__device__ __forceinline__ void tile_pass(
    const u16 (*__restrict__ Ks)[ALDP], const u16 (*__restrict__ Vt)[ALDP],
    u16* __restrict__ plrow,           // per-wave Pl base: [16][ALDP]
    TileState& ts, int kt0, bool diag, int quad, int c16)
{
    // ---- S^T = K Q^T: s[sub][r] = S^T[key = kt0+sub*16+quad*4+r][q = ts.qglob]
    f32x4 s[4];
#pragma unroll
    for (int sub = 0; sub < 4; sub++) {
        short8 kf0 = *reinterpret_cast<const short8*>(&Ks[sub * 16 + c16][0 * 32 + quad * 8]);
        short8 kf1 = *reinterpret_cast<const short8*>(&Ks[sub * 16 + c16][1 * 32 + quad * 8]);
        f32x4 acc = (f32x4){0.f, 0.f, 0.f, 0.f};
        acc = __builtin_amdgcn_mfma_f32_16x16x32_bf16(kf0, ts.qf[0], acc, 0, 0, 0);
        acc = __builtin_amdgcn_mfma_f32_16x16x32_bf16(kf1, ts.qf[1], acc, 0, 0, 0);
        s[sub] = acc;
    }

    if (diag) {
#pragma unroll
        for (int sub = 0; sub < 4; sub++)
#pragma unroll
            for (int r = 0; r < 4; r++)
                if (kt0 + sub * 16 + quad * 4 + r > ts.qglob) s[sub][r] = -INFINITY;
    }

    // ---- online softmax over keys (16 local + cross-quad shfl_xor)
    float mloc = -INFINITY;
#pragma unroll
    for (int sub = 0; sub < 4; sub++)
#pragma unroll
        for (int r = 0; r < 4; r++) mloc = fmaxf(mloc, s[sub][r]);
    mloc = fmaxf(mloc, __shfl_xor(mloc, 16));
    mloc = fmaxf(mloc, __shfl_xor(mloc, 32));
    const float mnew = fmaxf(ts.m, mloc);
    const float al   = __expf(ts.m - mnew);
    ts.m = mnew;

    float ls = 0.f;
#pragma unroll
    for (int sub = 0; sub < 4; sub++)
#pragma unroll
        for (int r = 0; r < 4; r++) {
            s[sub][r] = __expf(s[sub][r] - mnew);
            ls += s[sub][r];
        }
    ls += __shfl_xor(ls, 16);
    ls += __shfl_xor(ls, 32);
    ts.l = ts.l * al + ls;

    // ---- rescale O (row q = quad*4 + r takes al of that q from lanes 0..15)
#pragma unroll
    for (int r = 0; r < 4; r++) {
        const float alr = __shfl(al, quad * 4 + r);
#pragma unroll
        for (int d = 0; d < 4; d++) ts.O[d][r] *= alr;
    }

    // ---- P: write packed rows to per-wave LDS (keys sub*16+quad*4..+3 consecutive)
#pragma unroll
    for (int sub = 0; sub < 4; sub++) {
        u32 lo = (u32)f2b(s[sub][0]) | ((u32)f2b(s[sub][1]) << 16);
        u32 hi = (u32)f2b(s[sub][2]) | ((u32)f2b(s[sub][3]) << 16);
        *reinterpret_cast<uint2*>(plrow + c16 * ALDP + sub * 16 + quad * 4) =
            make_uint2(lo, hi);
    }
    // A-layout read back (wave-local; compiler orders via lgkmcnt)
    short8 pf[2];
#pragma unroll
    for (int c = 0; c < 2; c++)
        pf[c] = *reinterpret_cast<const short8*>(plrow + c16 * ALDP + c * 32 + quad * 8);

    // ---- O += P V
#pragma unroll
    for (int dsub = 0; dsub < 4; dsub++) {
#pragma unroll
        for (int c = 0; c < 2; c++) {
            short8 vf = *reinterpret_cast<const short8*>(&Vt[dsub * 16 + c16][c * 32 + quad * 8]);
            ts.O[dsub] = __builtin_amdgcn_mfma_f32_16x16x32_bf16(pf[c], vf, ts.O[dsub], 0, 0, 0);
        }
    }
}

// waves_per_eu(4,4): pin exactly 4 waves/EU -> 128-VGPR budget. Prevents the
// allocator's 64-VGPR/8-wave choice that spilled ~300 MB/launch to scratch (R8).
__global__ __launch_bounds__(256) __attribute__((amdgpu_waves_per_eu(4, 4)))
void attn_flash(const u16* __restrict__ qkv, u16* __restrict__ out)
{
    constexpr int T = 2048, C = 1024, C3 = 3072;

    __shared__ u16 Ks[64][ALDP];      // K-tile row-major [key][d]
    __shared__ u16 Vt[64][ALDP];      // V-tile transposed [d][key]
    __shared__ u16 Pl[4][16][ALDP];   // per-wave P scratch

    const int tid  = threadIdx.x;
    const int w    = tid >> 6;
    const int lane = tid & 63;
    const int quad = lane >> 4;
    const int c16  = lane & 15;

    const int qtA = blockIdx.x;        // 0..15  (light tile)
    const int qtB = 31 - qtA;          // 16..31 (heavy tile)
    const int bh  = blockIdx.y;
    const int h   = bh & 15;
    const int b   = bh >> 4;

    TileState A, B;
    A.qglob = qtA * 64 + w * 16 + c16;
    B.qglob = qtB * 64 + w * 16 + c16;
    A.m = B.m = -INFINITY;
    A.l = B.l = 0.f;
#pragma unroll
    for (int d = 0; d < 4; d++) {
        A.O[d] = (f32x4){0.f, 0.f, 0.f, 0.f};
        B.O[d] = (f32x4){0.f, 0.f, 0.f, 0.f};
    }
    // Q fragments pre-scaled by 1/sqrt(64) = 0.125 (exact in bf16)
#pragma unroll
    for (int c = 0; c < 2; c++) {
        short8 ra = *reinterpret_cast<const short8*>(
            qkv + (size_t)(b * T + A.qglob) * C3 + h * 64 + c * 32 + quad * 8);
        short8 rb = *reinterpret_cast<const short8*>(
            qkv + (size_t)(b * T + B.qglob) * C3 + h * 64 + c * 32 + quad * 8);
#pragma unroll
        for (int j = 0; j < 8; j++) {
            A.qf[c][j] = (short)f2b(b2f((u16)ra[j]) * 0.125f);
            B.qf[c][j] = (short)f2b(b2f((u16)rb[j]) * 0.125f);
        }
    }

    // staging coordinates
    const int kr  = tid >> 2, kc = (tid & 3) * 16;   // K: row kr, cols kc..+15
    const int vkp = tid & 31, vdg = (tid >> 5) * 8;  // V: keys 2vkp,2vkp+1, d vdg..+7
    const u16* baseK = qkv + (size_t)(b * T + kr) * C3 + C + h * 64 + kc;
    const u16* baseV = qkv + (size_t)(b * T + 2 * vkp) * C3 + 2 * C + h * 64 + vdg;

    u16* plrow = &Pl[w][0][0];

    for (int kt = 0; kt <= qtB; kt++) {
        const int kt0 = kt * 64;
        __syncthreads();   // previous tile's LDS reads complete
        {
            const uint4* gp = reinterpret_cast<const uint4*>(baseK + (size_t)kt0 * C3);
            uint4 ka = gp[0], kb = gp[1];
            const u16* g0 = baseV + (size_t)kt0 * C3;
            uint4 va = *reinterpret_cast<const uint4*>(g0);
            uint4 vb = *reinterpret_cast<const uint4*>(g0 + C3);
            *reinterpret_cast<uint4*>(&Ks[kr][kc])     = ka;
            *reinterpret_cast<uint4*>(&Ks[kr][kc + 8]) = kb;
            const u16* p0 = reinterpret_cast<const u16*>(&va);
            const u16* p1 = reinterpret_cast<const u16*>(&vb);
#pragma unroll
            for (int i = 0; i < 8; i++)
                *reinterpret_cast<u32*>(&Vt[vdg + i][2 * vkp]) =
                    (u32)p0[i] | ((u32)p1[i] << 16);
        }
        __syncthreads();

        tile_pass(Ks, Vt, plrow, B, kt0, kt == qtB, quad, c16);
        if (kt <= qtA)
            tile_pass(Ks, Vt, plrow, A, kt0, kt == qtA, quad, c16);
    }

    // ---- epilogue: O rows are q = quad*4 + r, cols d = dsub*16 + c16
    const float invA = 1.0f / A.l;
    const float invB = 1.0f / B.l;
#pragma unroll
    for (int r = 0; r < 4; r++) {
        const float iAr = __shfl(invA, quad * 4 + r);
        const float iBr = __shfl(invB, quad * 4 + r);
        const int qA = qtA * 64 + w * 16 + quad * 4 + r;
        const int qB = qtB * 64 + w * 16 + quad * 4 + r;
#pragma unroll
        for (int dsub = 0; dsub < 4; dsub++) {
            out[(size_t)(b * T + qA) * C + h * 64 + dsub * 16 + c16] =
                f2b(A.O[dsub][r] * iAr);
            out[(size_t)(b * T + qB) * C + h * 64 + dsub * 16 + c16] =
                f2b(B.O[dsub][r] * iBr);
        }
    }
}

// ---------- launcher ----------
extern "C" void kernel_launch(void* const* d_in, const int* in_sizes, int n_in,
                              void* d_out, int out_size, void* d_ws, size_t ws_size,
                              hipStream_t stream)
{
    constexpr int B = 4, T = 2048, C = 1024;
    constexpr int M = B * T;          // 8192
    const float* x      = (const float*)d_in[0];
    const float* W_attn = (const float*)d_in[1];
    const float* b_attn = (const float*)d_in[2];
    const float* W_proj = (const float*)d_in[3];
    const float* b_proj = (const float*)d_in[4];
    float* out = (float*)d_out;

    // workspace layout: qkv | {xb / attn_o aliased} | Wt_attn | Wt_proj
    char* p = (char*)d_ws;
    u16* qkv     = (u16*)p;                 p += (size_t)M * 3 * C * sizeof(u16);
    u16* xb      = (u16*)p;
    u16* attn_o  = (u16*)p;                 p += (size_t)M * C * sizeof(u16);
    u16* Wt_attn = (u16*)p;                 p += (size_t)3 * C * C * sizeof(u16);
    u16* Wt_proj = (u16*)p;

    cast_bf16<<<dim3(M * C / (256 * 8)), 256, 0, stream>>>(x, xb, M * C);
    transpose_cast<<<dim3(3 * C / 32, C / 32), 256, 0, stream>>>(W_attn, Wt_attn, C, 3 * C);
    transpose_cast<<<dim3(C / 32, C / 32), 256, 0, stream>>>(W_proj, Wt_proj, C, C);

    gemm_mfma<u16><<<dim3(3 * C / 128, M / 128), 256, 0, stream>>>(
        xb, Wt_attn, b_attn, qkv, M, 3 * C, C);

    attn_flash<<<dim3(16, B * 16), 256, 0, stream>>>(qkv, attn_o);

    gemm_mfma<float><<<dim3(C / 128, M / 128), 256, 0, stream>>>(
        attn_o, Wt_proj, b_proj, out, M, C, C);
}

// Round 10
// 303.980 us; speedup vs baseline: 1.0939x; 1.0939x over previous
//
#include <hip/hip_runtime.h>
#include <hip/hip_bf16.h>
#include <stdint.h>

typedef unsigned short u16;
typedef unsigned int   u32;

using short8 = __attribute__((ext_vector_type(8))) short;
using f32x4  = __attribute__((ext_vector_type(4))) float;

// ---------- bf16 helpers (raw-bit, RNE store) ----------
__device__ __forceinline__ float b2f(u32 u) {
    union { u32 i; float f; } v;
    v.i = u << 16;
    return v.f;
}
__device__ __forceinline__ u16 f2b(float f) {
    union { float f; u32 i; } v; v.f = f;
    u32 x = v.i;
    x += 0x7fffu + ((x >> 16) & 1u);   // round-to-nearest-even
    return (u16)(x >> 16);
}

// ---------- async global->LDS, 16B per lane ----------
__device__ __forceinline__ void gll16(const u16* g, u16* l) {
    __builtin_amdgcn_global_load_lds(
        (const __attribute__((address_space(1))) void*)g,
        (__attribute__((address_space(3))) void*)l, 16, 0, 0);
}

// ---------- prep: fp32 -> bf16 elementwise (8 elems/thread) ----------
__global__ __launch_bounds__(256)
void cast_bf16(const float* __restrict__ in, u16* __restrict__ out, int n)
{
    const int i = (blockIdx.x * 256 + threadIdx.x) * 8;
    if (i >= n) return;
    const float4 a = *reinterpret_cast<const float4*>(in + i);
    const float4 b = *reinterpret_cast<const float4*>(in + i + 4);
    u32 p0 = (u32)f2b(a.x) | ((u32)f2b(a.y) << 16);
    u32 p1 = (u32)f2b(a.z) | ((u32)f2b(a.w) << 16);
    u32 p2 = (u32)f2b(b.x) | ((u32)f2b(b.y) << 16);
    u32 p3 = (u32)f2b(b.z) | ((u32)f2b(b.w) << 16);
    *reinterpret_cast<uint4*>(out + i) = make_uint4(p0, p1, p2, p3);
}

// ---------- prep: W[R,Ncols] fp32 -> Wt[Ncols,R] bf16 (32x32 LDS tiles) ----------
__global__ __launch_bounds__(256)
void transpose_cast(const float* __restrict__ W, u16* __restrict__ Wt, int R, int Ncols)
{
    __shared__ float t[32][33];
    const int c0 = blockIdx.x * 32, r0 = blockIdx.y * 32;
    const int lx = threadIdx.x & 31, ly = threadIdx.x >> 5;   // 32 x 8
#pragma unroll
    for (int i = 0; i < 4; i++) {
        const int r = ly + i * 8;
        t[r][lx] = W[(size_t)(r0 + r) * Ncols + c0 + lx];
    }
    __syncthreads();
#pragma unroll
    for (int i = 0; i < 4; i++) {
        const int c = ly + i * 8;
        Wt[(size_t)(c0 + c) * R + r0 + lx] = f2b(t[lx][c]);
    }
}

// ---------- MFMA GEMM: C[M,N] = A[M,K] @ Bt[N,K]^T + bias[N] ----------
template<typename OT>
__global__ __launch_bounds__(256)
void gemm_mfma(const u16* __restrict__ A, const u16* __restrict__ Bt,
               const float* __restrict__ bias, OT* __restrict__ C,
               int M, int N, int K)
{
    __shared__ u16 As[128 * 32];   // [row][k], row stride 32
    __shared__ u16 Bs[128 * 32];   // [col][k]

    const int tid  = threadIdx.x;
    const int w    = tid >> 6;
    const int lane = tid & 63;
    const int quad = lane >> 4;
    const int c16  = lane & 15;
    const int wr   = w >> 1, wc = w & 1;

    const int m0 = blockIdx.y * 128;
    const int n0 = blockIdx.x * 128;

    const int srow = w * 32 + (lane >> 2);
    const int skc  = (lane & 3) * 8;
    const u16* gA = A  + (size_t)(m0 + srow) * K + skc;
    const u16* gB = Bt + (size_t)(n0 + srow) * K + skc;
    u16* lA = As + w * 32 * 32 + lane * 8;
    u16* lB = Bs + w * 32 * 32 + lane * 8;

    f32x4 acc[4][4];
#pragma unroll
    for (int i = 0; i < 4; i++)
#pragma unroll
        for (int j = 0; j < 4; j++) acc[i][j] = (f32x4){0.f, 0.f, 0.f, 0.f};

    for (int k0 = 0; k0 < K; k0 += 32) {
        __syncthreads();
        gll16(gA + k0,                  lA);
        gll16(gA + k0 + 16 * (size_t)K, lA + 16 * 32);
        gll16(gB + k0,                  lB);
        gll16(gB + k0 + 16 * (size_t)K, lB + 16 * 32);
        __syncthreads();

        short8 af[4], bf[4];
#pragma unroll
        for (int i = 0; i < 4; i++)
            af[i] = *reinterpret_cast<const short8*>(&As[(wr * 64 + i * 16 + c16) * 32 + quad * 8]);
#pragma unroll
        for (int j = 0; j < 4; j++)
            bf[j] = *reinterpret_cast<const short8*>(&Bs[(wc * 64 + j * 16 + c16) * 32 + quad * 8]);
#pragma unroll
        for (int i = 0; i < 4; i++)
#pragma unroll
            for (int j = 0; j < 4; j++)
                acc[i][j] = __builtin_amdgcn_mfma_f32_16x16x32_bf16(af[i], bf[j], acc[i][j], 0, 0, 0);
    }

#pragma unroll
    for (int i = 0; i < 4; i++)
#pragma unroll
        for (int j = 0; j < 4; j++) {
            const int colg = n0 + wc * 64 + j * 16 + c16;
            const float bv = bias[colg];
#pragma unroll
            for (int r = 0; r < 4; r++) {
                const int rowg = m0 + wr * 64 + i * 16 + quad * 4 + r;
                const float v = acc[i][j][r] + bv;
                if constexpr (sizeof(OT) == 2)
                    ((u16*)C)[(size_t)rowg * N + colg] = f2b(v);
                else
                    ((float*)C)[(size_t)rowg * N + colg] = v;
            }
        }
}

// ---------- Flash attention: paired q-tiles processed in TWO PHASES ----------
// Block x handles q-tiles {31-x, x} SEQUENTIALLY (one TileState live at a time
// -> fits the 64-VGPR allocation, no scratch spill; R8's concurrent pair spilled
// ~300 MB/launch). Every block: exactly 33 stagings + 33 tile-passes.
// S^T = K.Q^T (row=key, col=q); P via per-wave LDS roundtrip (no barrier).
constexpr int ALDP = 72;   // LDS row pad (u16 units)

struct TileState {
    f32x4 O[4];
    float m, l;
    short8 qf[2];
    int qglob;
};

__device__ __forceinline__ void tile_pass(
    const u16 (*__restrict__ Ks)[ALDP], const u16 (*__restrict__ Vt)[ALDP],
    u16* __restrict__ plrow,           // per-wave Pl base: [16][ALDP]
    TileState& ts, int kt0, bool diag, int quad, int c16)
{
    // ---- S^T = K Q^T: s[sub][r] = S^T[key = kt0+sub*16+quad*4+r][q = ts.qglob]
    f32x4 s[4];
#pragma unroll
    for (int sub = 0; sub < 4; sub++) {
        short8 kf0 = *reinterpret_cast<const short8*>(&Ks[sub * 16 + c16][0 * 32 + quad * 8]);
        short8 kf1 = *reinterpret_cast<const short8*>(&Ks[sub * 16 + c16][1 * 32 + quad * 8]);
        f32x4 acc = (f32x4){0.f, 0.f, 0.f, 0.f};
        acc = __builtin_amdgcn_mfma_f32_16x16x32_bf16(kf0, ts.qf[0], acc, 0, 0, 0);
        acc = __builtin_amdgcn_mfma_f32_16x16x32_bf16(kf1, ts.qf[1], acc, 0, 0, 0);
        s[sub] = acc;
    }

    if (diag) {
#pragma unroll
        for (int sub = 0; sub < 4; sub++)
#pragma unroll
            for (int r = 0; r < 4; r++)
                if (kt0 + sub * 16 + quad * 4 + r > ts.qglob) s[sub][r] = -INFINITY;
    }

    // ---- online softmax over keys (16 local + cross-quad shfl_xor)
    float mloc = -INFINITY;
#pragma unroll
    for (int sub = 0; sub < 4; sub++)
#pragma unroll
        for (int r = 0; r < 4; r++) mloc = fmaxf(mloc, s[sub][r]);
    mloc = fmaxf(mloc, __shfl_xor(mloc, 16));
    mloc = fmaxf(mloc, __shfl_xor(mloc, 32));
    const float mnew = fmaxf(ts.m, mloc);
    const float al   = __expf(ts.m - mnew);
    ts.m = mnew;

    // exp + P-write per sub (frees s[sub] promptly), then reduce the sum
    float ls = 0.f;
#pragma unroll
    for (int sub = 0; sub < 4; sub++) {
#pragma unroll
        for (int r = 0; r < 4; r++) {
            s[sub][r] = __expf(s[sub][r] - mnew);
            ls += s[sub][r];
        }
        u32 lo = (u32)f2b(s[sub][0]) | ((u32)f2b(s[sub][1]) << 16);
        u32 hi = (u32)f2b(s[sub][2]) | ((u32)f2b(s[sub][3]) << 16);
        *reinterpret_cast<uint2*>(plrow + c16 * ALDP + sub * 16 + quad * 4) =
            make_uint2(lo, hi);
    }
    ls += __shfl_xor(ls, 16);
    ls += __shfl_xor(ls, 32);
    ts.l = ts.l * al + ls;

    // ---- rescale O (row q = quad*4 + r takes al of that q from lanes 0..15)
#pragma unroll
    for (int r = 0; r < 4; r++) {
        const float alr = __shfl(al, quad * 4 + r);
#pragma unroll
        for (int d = 0; d < 4; d++) ts.O[d][r] *= alr;
    }

    // A-layout read back (wave-local; compiler orders via lgkmcnt)
    short8 pf[2];
#pragma unroll
    for (int c = 0; c < 2; c++)
        pf[c] = *reinterpret_cast<const short8*>(plrow + c16 * ALDP + c * 32 + quad * 8);

    // ---- O += P V
#pragma unroll
    for (int dsub = 0; dsub < 4; dsub++) {
#pragma unroll
        for (int c = 0; c < 2; c++) {
            short8 vf = *reinterpret_cast<const short8*>(&Vt[dsub * 16 + c16][c * 32 + quad * 8]);
            ts.O[dsub] = __builtin_amdgcn_mfma_f32_16x16x32_bf16(pf[c], vf, ts.O[dsub], 0, 0, 0);
        }
    }
}

__global__ __launch_bounds__(256)
void attn_flash(const u16* __restrict__ qkv, u16* __restrict__ out)
{
    constexpr int T = 2048, C = 1024, C3 = 3072;

    __shared__ u16 Ks[64][ALDP];      // K-tile row-major [key][d]
    __shared__ u16 Vt[64][ALDP];      // V-tile transposed [d][key]
    __shared__ u16 Pl[4][16][ALDP];   // per-wave P scratch

    const int tid  = threadIdx.x;
    const int w    = tid >> 6;
    const int lane = tid & 63;
    const int quad = lane >> 4;
    const int c16  = lane & 15;

    const int qtA = blockIdx.x;        // 0..15  (light tile)
    const int qtB = 31 - qtA;          // 16..31 (heavy tile)
    const int bh  = blockIdx.y;
    const int h   = bh & 15;
    const int b   = bh >> 4;

    // staging coordinates
    const int kr  = tid >> 2, kc = (tid & 3) * 16;   // K: row kr, cols kc..+15
    const int vkp = tid & 31, vdg = (tid >> 5) * 8;  // V: keys 2vkp,2vkp+1, d vdg..+7
    const u16* baseK = qkv + (size_t)(b * T + kr) * C3 + C + h * 64 + kc;
    const u16* baseV = qkv + (size_t)(b * T + 2 * vkp) * C3 + 2 * C + h * 64 + vdg;

    u16* plrow = &Pl[w][0][0];

#pragma unroll 1
    for (int phase = 0; phase < 2; ++phase) {
        const int qt = phase ? qtA : qtB;

        TileState ts;
        ts.qglob = qt * 64 + w * 16 + c16;
        ts.m = -INFINITY;
        ts.l = 0.f;
#pragma unroll
        for (int d = 0; d < 4; d++) ts.O[d] = (f32x4){0.f, 0.f, 0.f, 0.f};
        // Q fragments pre-scaled by 1/sqrt(64) = 0.125 (exact in bf16)
#pragma unroll
        for (int c = 0; c < 2; c++) {
            short8 rq = *reinterpret_cast<const short8*>(
                qkv + (size_t)(b * T + ts.qglob) * C3 + h * 64 + c * 32 + quad * 8);
#pragma unroll
            for (int j = 0; j < 8; j++)
                ts.qf[c][j] = (short)f2b(b2f((u16)rq[j]) * 0.125f);
        }

        for (int kt = 0; kt <= qt; kt++) {
            const int kt0 = kt * 64;
            __syncthreads();   // previous tile's LDS reads complete
            {
                const uint4* gp = reinterpret_cast<const uint4*>(baseK + (size_t)kt0 * C3);
                uint4 ka = gp[0], kb = gp[1];
                const u16* g0 = baseV + (size_t)kt0 * C3;
                uint4 va = *reinterpret_cast<const uint4*>(g0);
                uint4 vb = *reinterpret_cast<const uint4*>(g0 + C3);
                *reinterpret_cast<uint4*>(&Ks[kr][kc])     = ka;
                *reinterpret_cast<uint4*>(&Ks[kr][kc + 8]) = kb;
                const u16* p0 = reinterpret_cast<const u16*>(&va);
                const u16* p1 = reinterpret_cast<const u16*>(&vb);
#pragma unroll
                for (int i = 0; i < 8; i++)
                    *reinterpret_cast<u32*>(&Vt[vdg + i][2 * vkp]) =
                        (u32)p0[i] | ((u32)p1[i] << 16);
            }
            __syncthreads();

            tile_pass(Ks, Vt, plrow, ts, kt0, kt == qt, quad, c16);
        }

        // ---- epilogue: O rows are q = quad*4 + r, cols d = dsub*16 + c16
        const float inv = 1.0f / ts.l;
#pragma unroll
        for (int r = 0; r < 4; r++) {
            const float invr = __shfl(inv, quad * 4 + r);
            const int qrow = qt * 64 + w * 16 + quad * 4 + r;
#pragma unroll
            for (int dsub = 0; dsub < 4; dsub++)
                out[(size_t)(b * T + qrow) * C + h * 64 + dsub * 16 + c16] =
                    f2b(ts.O[dsub][r] * invr);
        }
    }
}

// ---------- launcher ----------
extern "C" void kernel_launch(void* const* d_in, const int* in_sizes, int n_in,
                              void* d_out, int out_size, void* d_ws, size_t ws_size,
                              hipStream_t stream)
{
    constexpr int B = 4, T = 2048, C = 1024;
    constexpr int M = B * T;          // 8192
    const float* x      = (const float*)d_in[0];
    const float* W_attn = (const float*)d_in[1];
    const float* b_attn = (const float*)d_in[2];
    const float* W_proj = (const float*)d_in[3];
    const float* b_proj = (const float*)d_in[4];
    float* out = (float*)d_out;

    // workspace layout: qkv | {xb / attn_o aliased} | Wt_attn | Wt_proj
    char* p = (char*)d_ws;
    u16* qkv     = (u16*)p;                 p += (size_t)M * 3 * C * sizeof(u16);
    u16* xb      = (u16*)p;
    u16* attn_o  = (u16*)p;                 p += (size_t)M * C * sizeof(u16);
    u16* Wt_attn = (u16*)p;                 p += (size_t)3 * C * C * sizeof(u16);
    u16* Wt_proj = (u16*)p;

    cast_bf16<<<dim3(M * C / (256 * 8)), 256, 0, stream>>>(x, xb, M * C);
    transpose_cast<<<dim3(3 * C / 32, C / 32), 256, 0, stream>>>(W_attn, Wt_attn, C, 3 * C);
    transpose_cast<<<dim3(C / 32, C / 32), 256, 0, stream>>>(W_proj, Wt_proj, C, C);

    gemm_mfma<u16><<<dim3(3 * C / 128, M / 128), 256, 0, stream>>>(
        xb, Wt_attn, b_attn, qkv, M, 3 * C, C);

    attn_flash<<<dim3(16, B * 16), 256, 0, stream>>>(qkv, attn_o);

    gemm_mfma<float><<<dim3(C / 128, M / 128), 256, 0, stream>>>(
        attn_o, Wt_proj, b_proj, out, M, C, C);
}

// Round 11
// 298.719 us; speedup vs baseline: 1.1131x; 1.0176x over previous
//
#include <hip/hip_runtime.h>
#include <hip/hip_bf16.h>
#include <stdint.h>

typedef unsigned short u16;
typedef unsigned int   u32;

using short8 = __attribute__((ext_vector_type(8))) short;
using f32x4  = __attribute__((ext_vector_type(4))) float;

// ---------- bf16 helpers ----------
__device__ __forceinline__ float b2f(u32 u) {
    union { u32 i; float f; } v;
    v.i = u << 16;
    return v.f;
}
__device__ __forceinline__ u16 f2b(float f) {
    union { float f; u32 i; } v; v.f = f;
    u32 x = v.i;
    x += 0x7fffu + ((x >> 16) & 1u);   // round-to-nearest-even
    return (u16)(x >> 16);
}
// packed f32x2 -> bf16x2 via v_cvt_pk_bf16_f32 (lo in low half)
__device__ __forceinline__ u32 pkbf16(float lo, float hi) {
    __hip_bfloat162 h = __float22bfloat162_rn(float2{lo, hi});
    return *reinterpret_cast<u32*>(&h);
}
__device__ __forceinline__ float fexp2(float x) {
#if __has_builtin(__builtin_amdgcn_exp2f)
    return __builtin_amdgcn_exp2f(x);
#else
    return exp2f(x);
#endif
}
// combine lo16(a)|lo16(b)<<16 and hi16(a)|hi16(b)<<16 via v_perm_b32
__device__ __forceinline__ u32 perm_lo(u32 a, u32 b) {   // [b.b1,b.b0,a.b1,a.b0]
#if __has_builtin(__builtin_amdgcn_perm)
    return __builtin_amdgcn_perm(b, a, 0x05040100u);
#else
    return (a & 0xffffu) | (b << 16);
#endif
}
__device__ __forceinline__ u32 perm_hi(u32 a, u32 b) {   // [b.b3,b.b2,a.b3,a.b2]
#if __has_builtin(__builtin_amdgcn_perm)
    return __builtin_amdgcn_perm(b, a, 0x07060302u);
#else
    return (a >> 16) | (b & 0xffff0000u);
#endif
}

// ---------- async global->LDS, 16B per lane ----------
__device__ __forceinline__ void gll16(const u16* g, u16* l) {
    __builtin_amdgcn_global_load_lds(
        (const __attribute__((address_space(1))) void*)g,
        (__attribute__((address_space(3))) void*)l, 16, 0, 0);
}

// ---------- prep: fp32 -> bf16 elementwise (8 elems/thread) ----------
__global__ __launch_bounds__(256)
void cast_bf16(const float* __restrict__ in, u16* __restrict__ out, int n)
{
    const int i = (blockIdx.x * 256 + threadIdx.x) * 8;
    if (i >= n) return;
    const float4 a = *reinterpret_cast<const float4*>(in + i);
    const float4 b = *reinterpret_cast<const float4*>(in + i + 4);
    *reinterpret_cast<uint4*>(out + i) = make_uint4(
        pkbf16(a.x, a.y), pkbf16(a.z, a.w), pkbf16(b.x, b.y), pkbf16(b.z, b.w));
}

// ---------- prep: W[R,Ncols] fp32 -> Wt[Ncols,R] bf16 (32x32 LDS tiles) ----------
__global__ __launch_bounds__(256)
void transpose_cast(const float* __restrict__ W, u16* __restrict__ Wt, int R, int Ncols)
{
    __shared__ float t[32][33];
    const int c0 = blockIdx.x * 32, r0 = blockIdx.y * 32;
    const int lx = threadIdx.x & 31, ly = threadIdx.x >> 5;   // 32 x 8
#pragma unroll
    for (int i = 0; i < 4; i++) {
        const int r = ly + i * 8;
        t[r][lx] = W[(size_t)(r0 + r) * Ncols + c0 + lx];
    }
    __syncthreads();
#pragma unroll
    for (int i = 0; i < 4; i++) {
        const int c = ly + i * 8;
        Wt[(size_t)(c0 + c) * R + r0 + lx] = f2b(t[lx][c]);
    }
}

// ---------- MFMA GEMM: C[M,N] = A[M,K] @ Bt[N,K]^T + bias[N] ----------
template<typename OT>
__global__ __launch_bounds__(256)
void gemm_mfma(const u16* __restrict__ A, const u16* __restrict__ Bt,
               const float* __restrict__ bias, OT* __restrict__ C,
               int M, int N, int K)
{
    __shared__ u16 As[128 * 32];   // [row][k], row stride 32
    __shared__ u16 Bs[128 * 32];   // [col][k]

    const int tid  = threadIdx.x;
    const int w    = tid >> 6;
    const int lane = tid & 63;
    const int quad = lane >> 4;
    const int c16  = lane & 15;
    const int wr   = w >> 1, wc = w & 1;

    const int m0 = blockIdx.y * 128;
    const int n0 = blockIdx.x * 128;

    const int srow = w * 32 + (lane >> 2);
    const int skc  = (lane & 3) * 8;
    const u16* gA = A  + (size_t)(m0 + srow) * K + skc;
    const u16* gB = Bt + (size_t)(n0 + srow) * K + skc;
    u16* lA = As + w * 32 * 32 + lane * 8;
    u16* lB = Bs + w * 32 * 32 + lane * 8;

    f32x4 acc[4][4];
#pragma unroll
    for (int i = 0; i < 4; i++)
#pragma unroll
        for (int j = 0; j < 4; j++) acc[i][j] = (f32x4){0.f, 0.f, 0.f, 0.f};

    for (int k0 = 0; k0 < K; k0 += 32) {
        __syncthreads();
        gll16(gA + k0,                  lA);
        gll16(gA + k0 + 16 * (size_t)K, lA + 16 * 32);
        gll16(gB + k0,                  lB);
        gll16(gB + k0 + 16 * (size_t)K, lB + 16 * 32);
        __syncthreads();

        short8 af[4], bf[4];
#pragma unroll
        for (int i = 0; i < 4; i++)
            af[i] = *reinterpret_cast<const short8*>(&As[(wr * 64 + i * 16 + c16) * 32 + quad * 8]);
#pragma unroll
        for (int j = 0; j < 4; j++)
            bf[j] = *reinterpret_cast<const short8*>(&Bs[(wc * 64 + j * 16 + c16) * 32 + quad * 8]);
#pragma unroll
        for (int i = 0; i < 4; i++)
#pragma unroll
            for (int j = 0; j < 4; j++)
                acc[i][j] = __builtin_amdgcn_mfma_f32_16x16x32_bf16(af[i], bf[j], acc[i][j], 0, 0, 0);
    }

#pragma unroll
    for (int i = 0; i < 4; i++)
#pragma unroll
        for (int j = 0; j < 4; j++) {
            const int colg = n0 + wc * 64 + j * 16 + c16;
            const float bv = bias[colg];
#pragma unroll
            for (int r = 0; r < 4; r++) {
                const int rowg = m0 + wr * 64 + i * 16 + quad * 4 + r;
                const float v = acc[i][j][r] + bv;
                if constexpr (sizeof(OT) == 2)
                    ((u16*)C)[(size_t)rowg * N + colg] = f2b(v);
                else
                    ((float*)C)[(size_t)rowg * N + colg] = v;
            }
        }
}

// ---------- Flash attention: paired q-tiles, two sequential phases ----------
// Softmax runs in the exp2 domain: Q pre-scaled by (1/sqrt(64))*log2(e), so
// every exponential is a raw v_exp_f32 and P = exp2(s - m) equals exp(score-max).
constexpr int ALDP = 72;   // LDS row pad (u16 units)

struct TileState {
    f32x4 O[4];
    float m, l;
    short8 qf[2];
    int qglob;
};

__device__ __forceinline__ void tile_pass(
    const u16 (*__restrict__ Ks)[ALDP], const u16 (*__restrict__ Vt)[ALDP],
    u16* __restrict__ plrow,           // per-wave Pl base: [16][ALDP]
    TileState& ts, int kt0, bool diag, int quad, int c16)
{
    // ---- S^T = K Q^T: s[sub][r] = S^T[key = kt0+sub*16+quad*4+r][q = ts.qglob]
    f32x4 s[4];
#pragma unroll
    for (int sub = 0; sub < 4; sub++) {
        short8 kf0 = *reinterpret_cast<const short8*>(&Ks[sub * 16 + c16][0 * 32 + quad * 8]);
        short8 kf1 = *reinterpret_cast<const short8*>(&Ks[sub * 16 + c16][1 * 32 + quad * 8]);
        f32x4 acc = (f32x4){0.f, 0.f, 0.f, 0.f};
        acc = __builtin_amdgcn_mfma_f32_16x16x32_bf16(kf0, ts.qf[0], acc, 0, 0, 0);
        acc = __builtin_amdgcn_mfma_f32_16x16x32_bf16(kf1, ts.qf[1], acc, 0, 0, 0);
        s[sub] = acc;
    }

    if (diag) {
#pragma unroll
        for (int sub = 0; sub < 4; sub++)
#pragma unroll
            for (int r = 0; r < 4; r++)
                if (kt0 + sub * 16 + quad * 4 + r > ts.qglob) s[sub][r] = -INFINITY;
    }

    // ---- online softmax over keys (16 local + cross-quad shfl_xor), log2 domain
    float mloc = -INFINITY;
#pragma unroll
    for (int sub = 0; sub < 4; sub++)
#pragma unroll
        for (int r = 0; r < 4; r++) mloc = fmaxf(mloc, s[sub][r]);
    mloc = fmaxf(mloc, __shfl_xor(mloc, 16));
    mloc = fmaxf(mloc, __shfl_xor(mloc, 32));
    const float mnew = fmaxf(ts.m, mloc);
    const float al   = fexp2(ts.m - mnew);
    ts.m = mnew;

    // exp2 + packed P-write per sub, then reduce the sum
    float ls = 0.f;
#pragma unroll
    for (int sub = 0; sub < 4; sub++) {
#pragma unroll
        for (int r = 0; r < 4; r++) {
            s[sub][r] = fexp2(s[sub][r] - mnew);
            ls += s[sub][r];
        }
        *reinterpret_cast<uint2*>(plrow + c16 * ALDP + sub * 16 + quad * 4) =
            make_uint2(pkbf16(s[sub][0], s[sub][1]), pkbf16(s[sub][2], s[sub][3]));
    }
    ls += __shfl_xor(ls, 16);
    ls += __shfl_xor(ls, 32);
    ts.l = ts.l * al + ls;

    // ---- rescale O (row q = quad*4 + r takes al of that q from lanes 0..15)
#pragma unroll
    for (int r = 0; r < 4; r++) {
        const float alr = __shfl(al, quad * 4 + r);
#pragma unroll
        for (int d = 0; d < 4; d++) ts.O[d][r] *= alr;
    }

    // A-layout read back (wave-local; compiler orders via lgkmcnt)
    short8 pf[2];
#pragma unroll
    for (int c = 0; c < 2; c++)
        pf[c] = *reinterpret_cast<const short8*>(plrow + c16 * ALDP + c * 32 + quad * 8);

    // ---- O += P V
#pragma unroll
    for (int dsub = 0; dsub < 4; dsub++) {
#pragma unroll
        for (int c = 0; c < 2; c++) {
            short8 vf = *reinterpret_cast<const short8*>(&Vt[dsub * 16 + c16][c * 32 + quad * 8]);
            ts.O[dsub] = __builtin_amdgcn_mfma_f32_16x16x32_bf16(pf[c], vf, ts.O[dsub], 0, 0, 0);
        }
    }
}

__global__ __launch_bounds__(256)
void attn_flash(const u16* __restrict__ qkv, u16* __restrict__ out)
{
    constexpr int T = 2048, C = 1024, C3 = 3072;

    __shared__ u16 Ks[64][ALDP];      // K-tile row-major [key][d]
    __shared__ u16 Vt[64][ALDP];      // V-tile transposed [d][key]
    __shared__ u16 Pl[4][16][ALDP];   // per-wave P scratch

    const int tid  = threadIdx.x;
    const int w    = tid >> 6;
    const int lane = tid & 63;
    const int quad = lane >> 4;
    const int c16  = lane & 15;

    const int qtA = blockIdx.x;        // 0..15  (light tile)
    const int qtB = 31 - qtA;          // 16..31 (heavy tile)
    const int bh  = blockIdx.y;
    const int h   = bh & 15;
    const int b   = bh >> 4;

    // staging coordinates
    const int kr  = tid >> 2, kc = (tid & 3) * 16;   // K: row kr, cols kc..+15
    const int vkp = tid & 31, vdg = (tid >> 5) * 8;  // V: keys 2vkp,2vkp+1, d vdg..+7
    const u16* baseK = qkv + (size_t)(b * T + kr) * C3 + C + h * 64 + kc;
    const u16* baseV = qkv + (size_t)(b * T + 2 * vkp) * C3 + 2 * C + h * 64 + vdg;

    u16* plrow = &Pl[w][0][0];

#pragma unroll 1
    for (int phase = 0; phase < 2; ++phase) {
        const int qt = phase ? qtA : qtB;

        TileState ts;
        ts.qglob = qt * 64 + w * 16 + c16;
        ts.m = -INFINITY;
        ts.l = 0.f;
#pragma unroll
        for (int d = 0; d < 4; d++) ts.O[d] = (f32x4){0.f, 0.f, 0.f, 0.f};
        // Q fragments pre-scaled by (1/sqrt(64)) * log2(e)  [exp2-domain softmax]
        constexpr float QSCALE = 0.125f * 1.44269504089f;
#pragma unroll
        for (int c = 0; c < 2; c++) {
            short8 rq = *reinterpret_cast<const short8*>(
                qkv + (size_t)(b * T + ts.qglob) * C3 + h * 64 + c * 32 + quad * 8);
#pragma unroll
            for (int j = 0; j < 8; j++)
                ts.qf[c][j] = (short)f2b(b2f((u16)rq[j]) * QSCALE);
        }

        for (int kt = 0; kt <= qt; kt++) {
            const int kt0 = kt * 64;
            __syncthreads();   // previous tile's LDS reads complete
            {
                const uint4* gp = reinterpret_cast<const uint4*>(baseK + (size_t)kt0 * C3);
                uint4 ka = gp[0], kb = gp[1];
                const u16* g0 = baseV + (size_t)kt0 * C3;
                uint4 va = *reinterpret_cast<const uint4*>(g0);
                uint4 vb = *reinterpret_cast<const uint4*>(g0 + C3);
                *reinterpret_cast<uint4*>(&Ks[kr][kc])     = ka;
                *reinterpret_cast<uint4*>(&Ks[kr][kc + 8]) = kb;
                // V transpose-repack: one v_perm per output dword
                const u32* aw = reinterpret_cast<const u32*>(&va);
                const u32* bw = reinterpret_cast<const u32*>(&vb);
#pragma unroll
                for (int i = 0; i < 4; i++) {
                    *reinterpret_cast<u32*>(&Vt[vdg + 2 * i][2 * vkp])     = perm_lo(aw[i], bw[i]);
                    *reinterpret_cast<u32*>(&Vt[vdg + 2 * i + 1][2 * vkp]) = perm_hi(aw[i], bw[i]);
                }
            }
            __syncthreads();

            tile_pass(Ks, Vt, plrow, ts, kt0, kt == qt, quad, c16);
        }

        // ---- epilogue: O rows are q = quad*4 + r, cols d = dsub*16 + c16
        const float inv = 1.0f / ts.l;
#pragma unroll
        for (int r = 0; r < 4; r++) {
            const float invr = __shfl(inv, quad * 4 + r);
            const int qrow = qt * 64 + w * 16 + quad * 4 + r;
#pragma unroll
            for (int dsub = 0; dsub < 4; dsub++)
                out[(size_t)(b * T + qrow) * C + h * 64 + dsub * 16 + c16] =
                    f2b(ts.O[dsub][r] * invr);
        }
    }
}

// ---------- launcher ----------
extern "C" void kernel_launch(void* const* d_in, const int* in_sizes, int n_in,
                              void* d_out, int out_size, void* d_ws, size_t ws_size,
                              hipStream_t stream)
{
    constexpr int B = 4, T = 2048, C = 1024;
    constexpr int M = B * T;          // 8192
    const float* x      = (const float*)d_in[0];
    const float* W_attn = (const float*)d_in[1];
    const float* b_attn = (const float*)d_in[2];
    const float* W_proj = (const float*)d_in[3];
    const float* b_proj = (const float*)d_in[4];
    float* out = (float*)d_out;

    // workspace layout: qkv | {xb / attn_o aliased} | Wt_attn | Wt_proj
    char* p = (char*)d_ws;
    u16* qkv     = (u16*)p;                 p += (size_t)M * 3 * C * sizeof(u16);
    u16* xb      = (u16*)p;
    u16* attn_o  = (u16*)p;                 p += (size_t)M * C * sizeof(u16);
    u16* Wt_attn = (u16*)p;                 p += (size_t)3 * C * C * sizeof(u16);
    u16* Wt_proj = (u16*)p;

    cast_bf16<<<dim3(M * C / (256 * 8)), 256, 0, stream>>>(x, xb, M * C);
    transpose_cast<<<dim3(3 * C / 32, C / 32), 256, 0, stream>>>(W_attn, Wt_attn, C, 3 * C);
    transpose_cast<<<dim3(C / 32, C / 32), 256, 0, stream>>>(W_proj, Wt_proj, C, C);

    gemm_mfma<u16><<<dim3(3 * C / 128, M / 128), 256, 0, stream>>>(
        xb, Wt_attn, b_attn, qkv, M, 3 * C, C);

    attn_flash<<<dim3(16, B * 16), 256, 0, stream>>>(qkv, attn_o);

    gemm_mfma<float><<<dim3(C / 128, M / 128), 256, 0, stream>>>(
        attn_o, Wt_proj, b_proj, out, M, C, C);
}